// Round 1
// baseline (761.353 us; speedup 1.0000x reference)
//
#include <hip/hip_runtime.h>
#include <hip/hip_bf16.h>
#include <math.h>

#define NN 3072
#define NU 1024
#define NI 2048
#define DD 128
#define BB 8192
#define GAMMA_F 0.2f

typedef __attribute__((ext_vector_type(8))) short short8;
typedef __attribute__((ext_vector_type(4))) float f32x4;

// async global->LDS, 16B per lane; LDS dst = wave-uniform base + lane*16
#define GLDS16(g, l)                                                          \
  __builtin_amdgcn_global_load_lds(                                           \
      (__attribute__((address_space(1))) void*)(g),                           \
      (__attribute__((address_space(3))) void*)(l), 16, 0, 0)

// ---------------------------------------------------------------------------
// Convert fp32 matrix to bf16 (optional straight copy) + bf16 transpose.
// grid (96,96), block (32,8)
__global__ void convert_transpose(const float* __restrict__ src,
                                  __hip_bfloat16* __restrict__ dstS,
                                  __hip_bfloat16* __restrict__ dstT) {
  __shared__ float tile[32][33];
  int bx = blockIdx.x * 32, by = blockIdx.y * 32;
  int tx = threadIdx.x, ty = threadIdx.y;
  for (int r = ty; r < 32; r += 8) {
    float v = src[(size_t)(by + r) * NN + bx + tx];
    tile[r][tx] = v;
    if (dstS) dstS[(size_t)(by + r) * NN + bx + tx] = __float2bfloat16(v);
  }
  __syncthreads();
  for (int r = ty; r < 32; r += 8) {
    dstT[(size_t)(bx + r) * NN + by + tx] = __float2bfloat16(tile[tx][r]);
  }
}

// ---------------------------------------------------------------------------
// C(MxN fp32) = Abf(MxK bf16, row-major) * Btb(NxK bf16, row-major = B^T)
// 128x128 tile, BK=32, 4 waves (2x2), each wave 4x4 frags of 16x16x32 MFMA.
// LDS chunk layout: 8 mtiles x 64 chunks x 16B; chunk l of mtile mt holds
// A[mt*16 + (l&15)][ (l>>4)*8 .. +8 ) so frag read = base + lane*16 (b128).
__global__ __launch_bounds__(256) void gemm_bt(
    const __hip_bfloat16* __restrict__ Ag,
    const __hip_bfloat16* __restrict__ Btg,
    float* __restrict__ Cg) {
  __shared__ __align__(16) short As[4096];  // 8 KB
  __shared__ __align__(16) short Bs[4096];  // 8 KB

  const int tid = threadIdx.x;
  const int wave = tid >> 6;
  const int lane = tid & 63;
  const int rowBase = blockIdx.y * 128;
  const int colBase = blockIdx.x * 128;
  const int wr = wave >> 1, wc = wave & 1;
  const int lrow = lane & 15, lq = lane >> 4;

  f32x4 acc[4][4];
  for (int i = 0; i < 4; ++i)
    for (int j = 0; j < 4; ++j) acc[i][j] = (f32x4){0.f, 0.f, 0.f, 0.f};

  const __hip_bfloat16* aSrc =
      Ag + (size_t)(rowBase + wave * 16 + lrow) * NN + lq * 8;
  const __hip_bfloat16* bSrc =
      Btg + (size_t)(colBase + wave * 16 + lrow) * NN + lq * 8;
  short* aD0 = &As[wave * 512];
  short* aD1 = &As[(4 + wave) * 512];
  short* bD0 = &Bs[wave * 512];
  short* bD1 = &Bs[(4 + wave) * 512];

  for (int kt = 0; kt < NN; kt += 32) {
    GLDS16(aSrc + kt, aD0);
    GLDS16(aSrc + (size_t)64 * NN + kt, aD1);
    GLDS16(bSrc + kt, bD0);
    GLDS16(bSrc + (size_t)64 * NN + kt, bD1);
    __syncthreads();
    short8 af[4], bf[4];
    for (int i = 0; i < 4; ++i)
      af[i] = *(const short8*)&As[(wr * 4 + i) * 512 + lane * 8];
    for (int j = 0; j < 4; ++j)
      bf[j] = *(const short8*)&Bs[(wc * 4 + j) * 512 + lane * 8];
    for (int i = 0; i < 4; ++i)
      for (int j = 0; j < 4; ++j)
        acc[i][j] = __builtin_amdgcn_mfma_f32_16x16x32_bf16(af[i], bf[j],
                                                            acc[i][j], 0, 0, 0);
    __syncthreads();
  }
  // C/D layout: col = lane&15, row = (lane>>4)*4 + reg
  for (int i = 0; i < 4; ++i) {
    int r0 = rowBase + (wr * 4 + i) * 16 + lq * 4;
    for (int j = 0; j < 4; ++j) {
      int c0 = colBase + (wc * 4 + j) * 16 + lrow;
      for (int r = 0; r < 4; ++r)
        Cg[(size_t)(r0 + r) * NN + c0] = acc[i][j][r];
    }
  }
}

// ---------------------------------------------------------------------------
// Per-row top-64 of 3072 nonneg fp32 via exact 31-bit radix select.
// One block (256 thr) per row; 12 values/thread in registers.
__global__ __launch_bounds__(256) void topk_rows(const float* __restrict__ M,
                                                 int* __restrict__ outCnt,
                                                 int* __restrict__ outIdx,
                                                 float* __restrict__ outVal) {
  int row = blockIdx.x;
  int tid = threadIdx.x;
  const float* rp = M + (size_t)row * NN;
  unsigned v[12];
  for (int j = 0; j < 12; ++j) v[j] = __float_as_uint(rp[tid + j * 256]);

  __shared__ int red[4];
  __shared__ int total;
  __shared__ int cnt;
  unsigned t = 0;
  for (int b = 30; b >= 0; --b) {
    unsigned cand = t | (1u << b);
    int c = 0;
    for (int j = 0; j < 12; ++j) c += (v[j] >= cand) ? 1 : 0;
    for (int off = 32; off; off >>= 1) c += __shfl_down(c, off, 64);
    __syncthreads();
    if ((tid & 63) == 0) red[tid >> 6] = c;
    __syncthreads();
    if (tid == 0) total = red[0] + red[1] + red[2] + red[3];
    __syncthreads();
    if (total >= 64) t = cand;
  }
  if (tid == 0) cnt = 0;
  __syncthreads();
  for (int j = 0; j < 12; ++j) {
    if (v[j] >= t) {
      int p = atomicAdd(&cnt, 1);
      if (p < 128) {
        outIdx[(size_t)row * 128 + p] = tid + j * 256;
        outVal[(size_t)row * 128 + p] = __uint_as_float(v[j]);
      }
    }
  }
  __syncthreads();
  if (tid == 0) outCnt[row] = cnt < 128 ? cnt : 128;
}

// ---------------------------------------------------------------------------
__global__ __launch_bounds__(256) void matvec(const float* __restrict__ A,
                                              const float* __restrict__ x,
                                              const float* __restrict__ u,
                                              float* __restrict__ tout,
                                              float* __restrict__ wacc) {
  int row = blockIdx.x, tid = threadIdx.x;
  const float* rp = A + (size_t)row * NN;
  float s = 0.f;
  for (int j = tid; j < NN; j += 256) s += rp[j] * x[j];
  for (int off = 32; off; off >>= 1) s += __shfl_down(s, off, 64);
  __shared__ float red[4];
  if ((tid & 63) == 0) red[tid >> 6] = s;
  __syncthreads();
  if (tid == 0) {
    float tot = red[0] + red[1] + red[2] + red[3];
    tout[row] = tot;
    atomicAdd(wacc, u[row] * tot);
  }
}

__global__ void dot_uv(const float* __restrict__ u, const float* __restrict__ v,
                       float* __restrict__ wacc0) {
  int tid = threadIdx.x;
  float s = 0.f;
  for (int j = tid; j < NN; j += 256) s += u[j] * v[j];
  for (int off = 32; off; off >>= 1) s += __shfl_down(s, off, 64);
  __shared__ float red[4];
  if ((tid & 63) == 0) red[tid >> 6] = s;
  __syncthreads();
  if (tid == 0) wacc0[0] = red[0] + red[1] + red[2] + red[3];
}

__global__ void init_ws(float* wacc) {
  if (threadIdx.x < 4) wacc[threadIdx.x] = 0.f;
}

__global__ void attn_kernel(const float* __restrict__ wacc,
                            float* __restrict__ aw) {
  float w0 = wacc[0], w1 = wacc[1], w2 = wacc[2], w3 = wacc[3];
  float s = w0 + w1 + w2 + w3;
  w0 /= s; w1 /= s; w2 /= s; w3 /= s;
  float m = fmaxf(fmaxf(w0, w1), fmaxf(w2, w3));
  float e0 = expf(w0 - m), e1 = expf(w1 - m), e2 = expf(w2 - m),
        e3 = expf(w3 - m);
  float se = e0 + e1 + e2 + e3;
  aw[0] = e0 / se; aw[1] = e1 / se; aw[2] = e2 / se; aw[3] = e3 / se;
  aw[4] = GAMMA_F * (aw[1] + aw[2] + aw[3]);
}

// ---------------------------------------------------------------------------
// light_out[row][d] = aw0*E[row][d] + GAMMA*(aw1+aw2+aw3)*E0[row][d]
//                     + sum_l aw[l+1] * sum_k val * E[idx][d]
__global__ __launch_bounds__(128) void build_light(
    const float* __restrict__ allE, const float* __restrict__ allE0,
    const float* __restrict__ aw, const int* __restrict__ cnts,
    const int* __restrict__ tIdx, const float* __restrict__ tVal,
    float* __restrict__ lightOut) {
  int row = blockIdx.x, d = threadIdx.x;
  float acc = aw[0] * allE[(size_t)row * DD + d] +
              aw[4] * allE0[(size_t)row * DD + d];
  __shared__ int sIdx[128];
  __shared__ float sVal[128];
  for (int l = 0; l < 3; ++l) {
    int c = cnts[l * NN + row];
    const int* ip = tIdx + ((size_t)l * NN + row) * 128;
    const float* vp = tVal + ((size_t)l * NN + row) * 128;
    __syncthreads();
    if (d < c) { sIdx[d] = ip[d]; sVal[d] = vp[d]; }
    __syncthreads();
    float al = aw[l + 1];
    float la = 0.f;
    for (int k = 0; k < c; ++k) la += sVal[k] * allE[(size_t)sIdx[k] * DD + d];
    acc += al * la;
  }
  lightOut[(size_t)row * DD + d] = acc;
}

__global__ __launch_bounds__(64) void out_dot(const int* __restrict__ users,
                                              const int* __restrict__ items,
                                              const float* __restrict__ lightOut,
                                              float* __restrict__ out) {
  int b = blockIdx.x, lane = threadIdx.x;
  const float* up = lightOut + (size_t)users[b] * DD;
  const float* ip = lightOut + (size_t)(NU + items[b]) * DD;
  float s = up[lane] * ip[lane] + up[lane + 64] * ip[lane + 64];
  for (int off = 32; off; off >>= 1) s += __shfl_down(s, off, 64);
  if (lane == 0) out[b] = s;
}

// ---------------------------------------------------------------------------
extern "C" void kernel_launch(void* const* d_in, const int* in_sizes, int n_in,
                              void* d_out, int out_size, void* d_ws,
                              size_t ws_size, hipStream_t stream) {
  const int* users = (const int*)d_in[0];
  const int* items = (const int*)d_in[1];
  const float* A = (const float*)d_in[2];
  const float* uemb = (const float*)d_in[3];
  const float* iemb = (const float*)d_in[4];
  const float* uemb0 = (const float*)d_in[5];
  const float* iemb0 = (const float*)d_in[6];
  const float* vu = (const float*)d_in[7];
  const float* vv = (const float*)d_in[8];
  float* out = (float*)d_out;

  char* ws = (char*)d_ws;
  size_t off = 0;
  auto alloc = [&](size_t bytes) -> void* {
    void* p = ws + off;
    off += (bytes + 255) & ~(size_t)255;
    return p;
  };
  float* allE = (float*)alloc((size_t)NN * DD * 4);
  float* allE0 = (float*)alloc((size_t)NN * DD * 4);
  __hip_bfloat16* Abf = (__hip_bfloat16*)alloc((size_t)NN * NN * 2);
  __hip_bfloat16* Btb = (__hip_bfloat16*)alloc((size_t)NN * NN * 2);
  float* C = (float*)alloc((size_t)NN * NN * 4);
  float* tvec = (float*)alloc((size_t)3 * NN * 4);
  float* wacc = (float*)alloc(256);
  float* aw = (float*)alloc(256);
  int* cnts = (int*)alloc((size_t)3 * NN * 4);
  int* tIdx = (int*)alloc((size_t)3 * NN * 128 * 4);
  float* tVal = (float*)alloc((size_t)3 * NN * 128 * 4);
  float* lightOut = (float*)alloc((size_t)NN * DD * 4);
  // total ~90 MB of ws

  // concat embeddings
  hipMemcpyAsync(allE, uemb, (size_t)NU * DD * 4, hipMemcpyDeviceToDevice,
                 stream);
  hipMemcpyAsync(allE + (size_t)NU * DD, iemb, (size_t)NI * DD * 4,
                 hipMemcpyDeviceToDevice, stream);
  hipMemcpyAsync(allE0, uemb0, (size_t)NU * DD * 4, hipMemcpyDeviceToDevice,
                 stream);
  hipMemcpyAsync(allE0 + (size_t)NU * DD, iemb0, (size_t)NI * DD * 4,
                 hipMemcpyDeviceToDevice, stream);

  init_ws<<<1, 64, 0, stream>>>(wacc);

  // A -> bf16 (straight + transposed)
  convert_transpose<<<dim3(96, 96), dim3(32, 8), 0, stream>>>(A, Abf, Btb);
  // A2 = A*A  (fp32 C)
  gemm_bt<<<dim3(24, 24), 256, 0, stream>>>(Abf, Btb, C);
  // top-64 of A (layer 0) and A2 (layer 1)
  topk_rows<<<NN, 256, 0, stream>>>(A, cnts, tIdx, tVal);
  topk_rows<<<NN, 256, 0, stream>>>(C, cnts + NN, tIdx + (size_t)NN * 128,
                                    tVal + (size_t)NN * 128);
  // A2^T bf16 (overwrite Btb)
  convert_transpose<<<dim3(96, 96), dim3(32, 8), 0, stream>>>(
      C, (__hip_bfloat16*)nullptr, Btb);
  // A3 = A*A2 (overwrite C)
  gemm_bt<<<dim3(24, 24), 256, 0, stream>>>(Abf, Btb, C);
  topk_rows<<<NN, 256, 0, stream>>>(C, cnts + 2 * NN,
                                    tIdx + (size_t)2 * NN * 128,
                                    tVal + (size_t)2 * NN * 128);

  // attention weights: w = [u.v, u.Av, u.A2v, u.A3v]
  dot_uv<<<1, 256, 0, stream>>>(vu, vv, wacc);
  matvec<<<NN, 256, 0, stream>>>(A, vv, vu, tvec, wacc + 1);
  matvec<<<NN, 256, 0, stream>>>(A, tvec, vu, tvec + NN, wacc + 2);
  matvec<<<NN, 256, 0, stream>>>(A, tvec + NN, vu, tvec + 2 * NN, wacc + 3);
  attn_kernel<<<1, 1, 0, stream>>>(wacc, aw);

  build_light<<<NN, 128, 0, stream>>>(allE, allE0, aw, cnts, tIdx, tVal,
                                      lightOut);
  out_dot<<<BB, 64, 0, stream>>>(users, items, lightOut, out);
}

// Round 2
// 688.165 us; speedup vs baseline: 1.1064x; 1.1064x over previous
//
#include <hip/hip_runtime.h>
#include <hip/hip_bf16.h>
#include <math.h>

#define NN 3072
#define NU 1024
#define NI 2048
#define DD 128
#define BB 8192
#define GAMMA_F 0.2f

typedef __attribute__((ext_vector_type(8))) short short8;
typedef __attribute__((ext_vector_type(4))) float f32x4;

// async global->LDS, 16B per lane; LDS dst = wave-uniform base + lane*16
#define GLDS16(g, l)                                                          \
  __builtin_amdgcn_global_load_lds(                                           \
      (__attribute__((address_space(1))) void*)(g),                           \
      (__attribute__((address_space(3))) void*)(l), 16, 0, 0)

static __device__ inline unsigned short bf16bits(float x) {
  union { __hip_bfloat16 h; unsigned short u; } cv;
  cv.h = __float2bfloat16(x);
  return cv.u;
}

// ---------------------------------------------------------------------------
// 64x64-tile convert/transpose. src = s0 (+ s1 if non-null, fused partial sum).
// dstS (optional): straight bf16 copy. dstT: bf16 transpose.
// block 256, grid (48,48)
__global__ __launch_bounds__(256) void conv_tr(const float* __restrict__ s0,
                                               const float* __restrict__ s1,
                                               __hip_bfloat16* __restrict__ dstS,
                                               __hip_bfloat16* __restrict__ dstT) {
  __shared__ float tile[64][65];
  const int bx = blockIdx.x * 64, by = blockIdx.y * 64;
  const int t = threadIdx.x;
  const int rr = t >> 4;          // 0..15
  const int c4 = (t & 15) * 4;    // col offset
  for (int it = 0; it < 4; ++it) {
    int r = rr + it * 16;
    float4 val = *(const float4*)(s0 + (size_t)(by + r) * NN + bx + c4);
    if (s1) {
      float4 w = *(const float4*)(s1 + (size_t)(by + r) * NN + bx + c4);
      val.x += w.x; val.y += w.y; val.z += w.z; val.w += w.w;
    }
    tile[r][c4] = val.x; tile[r][c4 + 1] = val.y;
    tile[r][c4 + 2] = val.z; tile[r][c4 + 3] = val.w;
    if (dstS) {
      ushort4 u;
      u.x = bf16bits(val.x); u.y = bf16bits(val.y);
      u.z = bf16bits(val.z); u.w = bf16bits(val.w);
      *(ushort4*)(dstS + (size_t)(by + r) * NN + bx + c4) = u;
    }
  }
  __syncthreads();
  for (int it = 0; it < 4; ++it) {
    int c = (t >> 4) + it * 16;
    int r0 = (t & 15) * 4;
    ushort4 u;
    u.x = bf16bits(tile[r0][c]);
    u.y = bf16bits(tile[r0 + 1][c]);
    u.z = bf16bits(tile[r0 + 2][c]);
    u.w = bf16bits(tile[r0 + 3][c]);
    *(ushort4*)(dstT + (size_t)(bx + c) * NN + by + r0) = u;
  }
}

// ---------------------------------------------------------------------------
// C(128x128 fp32 tile) = A(row-major bf16) * Bt(row-major bf16 = B^T), BK=32.
// Split-K over blockIdx.z: each part writes its own partial buffer.
__global__ __launch_bounds__(256) void gemm_bt(
    const __hip_bfloat16* __restrict__ Ag,
    const __hip_bfloat16* __restrict__ Btg,
    float* __restrict__ Cg, int kLen) {
  __shared__ __align__(16) short As[4096];  // 8 KB
  __shared__ __align__(16) short Bs[4096];  // 8 KB

  const int tid = threadIdx.x;
  const int wave = tid >> 6;
  const int lane = tid & 63;
  const int rowBase = blockIdx.y * 128;
  const int colBase = blockIdx.x * 128;
  const int wr = wave >> 1, wc = wave & 1;
  const int lrow = lane & 15, lq = lane >> 4;
  const int kStart = blockIdx.z * kLen;
  float* Cout = Cg + (size_t)blockIdx.z * NN * NN;

  f32x4 acc[4][4];
  for (int i = 0; i < 4; ++i)
    for (int j = 0; j < 4; ++j) acc[i][j] = (f32x4){0.f, 0.f, 0.f, 0.f};

  const __hip_bfloat16* aSrc =
      Ag + (size_t)(rowBase + wave * 16 + lrow) * NN + lq * 8;
  const __hip_bfloat16* bSrc =
      Btg + (size_t)(colBase + wave * 16 + lrow) * NN + lq * 8;
  short* aD0 = &As[wave * 512];
  short* aD1 = &As[(4 + wave) * 512];
  short* bD0 = &Bs[wave * 512];
  short* bD1 = &Bs[(4 + wave) * 512];

  for (int kt = kStart; kt < kStart + kLen; kt += 32) {
    GLDS16(aSrc + kt, aD0);
    GLDS16(aSrc + (size_t)64 * NN + kt, aD1);
    GLDS16(bSrc + kt, bD0);
    GLDS16(bSrc + (size_t)64 * NN + kt, bD1);
    __syncthreads();
    short8 af[4], bf[4];
    for (int i = 0; i < 4; ++i)
      af[i] = *(const short8*)&As[(wr * 4 + i) * 512 + lane * 8];
    for (int j = 0; j < 4; ++j)
      bf[j] = *(const short8*)&Bs[(wc * 4 + j) * 512 + lane * 8];
    for (int i = 0; i < 4; ++i)
      for (int j = 0; j < 4; ++j)
        acc[i][j] = __builtin_amdgcn_mfma_f32_16x16x32_bf16(af[i], bf[j],
                                                            acc[i][j], 0, 0, 0);
    __syncthreads();
  }
  // C/D layout: col = lane&15, row = (lane>>4)*4 + reg
  for (int i = 0; i < 4; ++i) {
    int r0 = rowBase + (wr * 4 + i) * 16 + lq * 4;
    for (int j = 0; j < 4; ++j) {
      int c0 = colBase + (wc * 4 + j) * 16 + lrow;
      for (int r = 0; r < 4; ++r)
        Cout[(size_t)(r0 + r) * NN + c0] = acc[i][j][r];
    }
  }
}

// ---------------------------------------------------------------------------
// Per-row top-64 via exact 31-bit radix select; ONE WAVE PER ROW, no barriers,
// no LDS. 256 threads = 4 waves = 4 rows per block; 48 values/lane in VGPRs.
// M1 non-null => select over (M0+M1) (fused split-K partial sum).
__global__ __launch_bounds__(256) void topk_rows(const float* __restrict__ M0,
                                                 const float* __restrict__ M1,
                                                 int* __restrict__ outCnt,
                                                 int* __restrict__ outIdx,
                                                 float* __restrict__ outVal) {
  const int row = blockIdx.x * 4 + (threadIdx.x >> 6);
  const int lane = threadIdx.x & 63;
  const float* r0 = M0 + (size_t)row * NN;
  unsigned v[48];
  if (M1) {
    const float* r1 = M1 + (size_t)row * NN;
#pragma unroll
    for (int j = 0; j < 48; ++j)
      v[j] = __float_as_uint(r0[lane + j * 64] + r1[lane + j * 64]);
  } else {
#pragma unroll
    for (int j = 0; j < 48; ++j) v[j] = __float_as_uint(r0[lane + j * 64]);
  }

  unsigned t = 0;
  for (int b = 30; b >= 0; --b) {
    unsigned cand = t | (1u << b);
    int c = 0;
#pragma unroll
    for (int j = 0; j < 48; ++j) c += (v[j] >= cand) ? 1 : 0;
    for (int off = 32; off; off >>= 1) c += __shfl_down(c, off, 64);
    c = __shfl(c, 0, 64);
    if (c >= 64) t = cand;
  }

  // ordered compaction via ballot
  int base = 0;
  int* oi = outIdx + (size_t)row * 128;
  float* ov = outVal + (size_t)row * 128;
#pragma unroll
  for (int j = 0; j < 48; ++j) {
    bool keep = v[j] >= t;
    unsigned long long m = __ballot(keep);
    if (keep) {
      int pos = base + __popcll(m & ((1ull << lane) - 1ull));
      if (pos < 128) {
        oi[pos] = lane + j * 64;
        ov[pos] = __uint_as_float(v[j]);
      }
    }
    base += __popcll(m);
  }
  if (lane == 0) outCnt[row] = base < 128 ? base : 128;
}

// ---------------------------------------------------------------------------
__global__ __launch_bounds__(256) void matvec(const float* __restrict__ A,
                                              const float* __restrict__ x,
                                              const float* __restrict__ u,
                                              float* __restrict__ tout,
                                              float* __restrict__ wacc) {
  int row = blockIdx.x, tid = threadIdx.x;
  const float* rp = A + (size_t)row * NN;
  float s = 0.f;
  for (int j = tid; j < NN; j += 256) s += rp[j] * x[j];
  for (int off = 32; off; off >>= 1) s += __shfl_down(s, off, 64);
  __shared__ float red[4];
  if ((tid & 63) == 0) red[tid >> 6] = s;
  __syncthreads();
  if (tid == 0) {
    float tot = red[0] + red[1] + red[2] + red[3];
    tout[row] = tot;
    atomicAdd(wacc, u[row] * tot);
  }
}

__global__ void dot_uv(const float* __restrict__ u, const float* __restrict__ v,
                       float* __restrict__ wacc0) {
  int tid = threadIdx.x;
  float s = 0.f;
  for (int j = tid; j < NN; j += 256) s += u[j] * v[j];
  for (int off = 32; off; off >>= 1) s += __shfl_down(s, off, 64);
  __shared__ float red[4];
  if ((tid & 63) == 0) red[tid >> 6] = s;
  __syncthreads();
  if (tid == 0) wacc0[0] = red[0] + red[1] + red[2] + red[3];
}

__global__ void init_ws(float* wacc) {
  if (threadIdx.x < 4) wacc[threadIdx.x] = 0.f;
}

__global__ void attn_kernel(const float* __restrict__ wacc,
                            float* __restrict__ aw) {
  float w0 = wacc[0], w1 = wacc[1], w2 = wacc[2], w3 = wacc[3];
  float s = w0 + w1 + w2 + w3;
  w0 /= s; w1 /= s; w2 /= s; w3 /= s;
  float m = fmaxf(fmaxf(w0, w1), fmaxf(w2, w3));
  float e0 = expf(w0 - m), e1 = expf(w1 - m), e2 = expf(w2 - m),
        e3 = expf(w3 - m);
  float se = e0 + e1 + e2 + e3;
  aw[0] = e0 / se; aw[1] = e1 / se; aw[2] = e2 / se; aw[3] = e3 / se;
  aw[4] = GAMMA_F * (aw[1] + aw[2] + aw[3]);
}

// ---------------------------------------------------------------------------
__global__ __launch_bounds__(128) void build_light(
    const float* __restrict__ allE, const float* __restrict__ allE0,
    const float* __restrict__ aw, const int* __restrict__ cnts,
    const int* __restrict__ tIdx, const float* __restrict__ tVal,
    float* __restrict__ lightOut) {
  int row = blockIdx.x, d = threadIdx.x;
  float acc = aw[0] * allE[(size_t)row * DD + d] +
              aw[4] * allE0[(size_t)row * DD + d];
  __shared__ int sIdx[128];
  __shared__ float sVal[128];
  for (int l = 0; l < 3; ++l) {
    int c = cnts[l * NN + row];
    const int* ip = tIdx + ((size_t)l * NN + row) * 128;
    const float* vp = tVal + ((size_t)l * NN + row) * 128;
    __syncthreads();
    if (d < c) { sIdx[d] = ip[d]; sVal[d] = vp[d]; }
    __syncthreads();
    float al = aw[l + 1];
    float la = 0.f;
    for (int k = 0; k < c; ++k) la += sVal[k] * allE[(size_t)sIdx[k] * DD + d];
    acc += al * la;
  }
  lightOut[(size_t)row * DD + d] = acc;
}

__global__ __launch_bounds__(64) void out_dot(const int* __restrict__ users,
                                              const int* __restrict__ items,
                                              const float* __restrict__ lightOut,
                                              float* __restrict__ out) {
  int b = blockIdx.x, lane = threadIdx.x;
  const float* up = lightOut + (size_t)users[b] * DD;
  const float* ip = lightOut + (size_t)(NU + items[b]) * DD;
  float s = up[lane] * ip[lane] + up[lane + 64] * ip[lane + 64];
  for (int off = 32; off; off >>= 1) s += __shfl_down(s, off, 64);
  if (lane == 0) out[b] = s;
}

// ---------------------------------------------------------------------------
extern "C" void kernel_launch(void* const* d_in, const int* in_sizes, int n_in,
                              void* d_out, int out_size, void* d_ws,
                              size_t ws_size, hipStream_t stream) {
  const int* users = (const int*)d_in[0];
  const int* items = (const int*)d_in[1];
  const float* A = (const float*)d_in[2];
  const float* uemb = (const float*)d_in[3];
  const float* iemb = (const float*)d_in[4];
  const float* uemb0 = (const float*)d_in[5];
  const float* iemb0 = (const float*)d_in[6];
  const float* vu = (const float*)d_in[7];
  const float* vv = (const float*)d_in[8];
  float* out = (float*)d_out;

  char* ws = (char*)d_ws;
  size_t off = 0;
  auto alloc = [&](size_t bytes) -> void* {
    void* p = ws + off;
    off += (bytes + 255) & ~(size_t)255;
    return p;
  };
  float* allE = (float*)alloc((size_t)NN * DD * 4);
  float* allE0 = (float*)alloc((size_t)NN * DD * 4);
  __hip_bfloat16* Abf = (__hip_bfloat16*)alloc((size_t)NN * NN * 2);
  __hip_bfloat16* Btb = (__hip_bfloat16*)alloc((size_t)NN * NN * 2);
  float* tvec = (float*)alloc((size_t)3 * NN * 4);
  float* wacc = (float*)alloc(256);
  float* aw = (float*)alloc(256);
  int* cnts = (int*)alloc((size_t)3 * NN * 4);
  int* tIdx = (int*)alloc((size_t)3 * NN * 128 * 4);
  float* tVal = (float*)alloc((size_t)3 * NN * 128 * 4);
  float* lightOut = (float*)alloc((size_t)NN * DD * 4);

  // split-K=2 if workspace holds two fp32 partial buffers, else 1
  const size_t cBytes = (size_t)NN * NN * 4;
  const bool split2 = (ws_size >= off + 2 * cBytes + 512);
  float* C0 = (float*)alloc(cBytes);
  float* C1 = split2 ? (float*)alloc(cBytes) : nullptr;
  const int kParts = split2 ? 2 : 1;
  const int kLen = NN / kParts;

  // concat embeddings
  hipMemcpyAsync(allE, uemb, (size_t)NU * DD * 4, hipMemcpyDeviceToDevice,
                 stream);
  hipMemcpyAsync(allE + (size_t)NU * DD, iemb, (size_t)NI * DD * 4,
                 hipMemcpyDeviceToDevice, stream);
  hipMemcpyAsync(allE0, uemb0, (size_t)NU * DD * 4, hipMemcpyDeviceToDevice,
                 stream);
  hipMemcpyAsync(allE0 + (size_t)NU * DD, iemb0, (size_t)NI * DD * 4,
                 hipMemcpyDeviceToDevice, stream);

  init_ws<<<1, 64, 0, stream>>>(wacc);

  // A -> bf16 (straight + transposed)
  conv_tr<<<dim3(48, 48), 256, 0, stream>>>(A, nullptr, Abf, Btb);
  // A2 = A*A (fp32 partials)
  gemm_bt<<<dim3(24, 24, kParts), 256, 0, stream>>>(Abf, Btb, C0, kLen);
  // top-64 of A (layer 0) and A2 (layer 1, fused partial sum)
  topk_rows<<<NN / 4, 256, 0, stream>>>(A, nullptr, cnts, tIdx, tVal);
  topk_rows<<<NN / 4, 256, 0, stream>>>(C0, C1, cnts + NN,
                                        tIdx + (size_t)NN * 128,
                                        tVal + (size_t)NN * 128);
  // A2^T bf16 (fused partial sum, overwrite Btb)
  conv_tr<<<dim3(48, 48), 256, 0, stream>>>(C0, C1, (__hip_bfloat16*)nullptr,
                                            Btb);
  // A3 = A*A2 (overwrite partials)
  gemm_bt<<<dim3(24, 24, kParts), 256, 0, stream>>>(Abf, Btb, C0, kLen);
  topk_rows<<<NN / 4, 256, 0, stream>>>(C0, C1, cnts + 2 * NN,
                                        tIdx + (size_t)2 * NN * 128,
                                        tVal + (size_t)2 * NN * 128);

  // attention weights: w = [u.v, u.Av, u.A2v, u.A3v]
  dot_uv<<<1, 256, 0, stream>>>(vu, vv, wacc);
  matvec<<<NN, 256, 0, stream>>>(A, vv, vu, tvec, wacc + 1);
  matvec<<<NN, 256, 0, stream>>>(A, tvec, vu, tvec + NN, wacc + 2);
  matvec<<<NN, 256, 0, stream>>>(A, tvec + NN, vu, tvec + 2 * NN, wacc + 3);
  attn_kernel<<<1, 1, 0, stream>>>(wacc, aw);

  build_light<<<NN, 128, 0, stream>>>(allE, allE0, aw, cnts, tIdx, tVal,
                                      lightOut);
  out_dot<<<BB, 64, 0, stream>>>(users, items, lightOut, out);
}

// Round 3
// 678.861 us; speedup vs baseline: 1.1215x; 1.0137x over previous
//
#include <hip/hip_runtime.h>
#include <hip/hip_bf16.h>
#include <math.h>

#define NN 3072
#define NU 1024
#define NI 2048
#define DD 128
#define BB 8192
#define GAMMA_F 0.2f

typedef __attribute__((ext_vector_type(8))) short short8;
typedef __attribute__((ext_vector_type(4))) float f32x4;

// async global->LDS, 16B per lane; LDS dst = wave-uniform base + lane*16
#define GLDS16(g, l)                                                          \
  __builtin_amdgcn_global_load_lds(                                           \
      (__attribute__((address_space(1))) void*)(g),                           \
      (__attribute__((address_space(3))) void*)(l), 16, 0, 0)

static __device__ inline unsigned short bf16bits(float x) {
  union { __hip_bfloat16 h; unsigned short u; } cv;
  cv.h = __float2bfloat16(x);
  return cv.u;
}

// ---------------------------------------------------------------------------
// 64x64-tile convert/transpose: A -> bf16 straight (dstS) + bf16 transpose
// (dstT). block 256, grid (48,48)
__global__ __launch_bounds__(256) void conv_tr(const float* __restrict__ s0,
                                               __hip_bfloat16* __restrict__ dstS,
                                               __hip_bfloat16* __restrict__ dstT) {
  __shared__ float tile[64][65];
  const int bx = blockIdx.x * 64, by = blockIdx.y * 64;
  const int t = threadIdx.x;
  const int rr = t >> 4;          // 0..15
  const int c4 = (t & 15) * 4;    // col offset
  for (int it = 0; it < 4; ++it) {
    int r = rr + it * 16;
    float4 val = *(const float4*)(s0 + (size_t)(by + r) * NN + bx + c4);
    tile[r][c4] = val.x; tile[r][c4 + 1] = val.y;
    tile[r][c4 + 2] = val.z; tile[r][c4 + 3] = val.w;
    ushort4 u;
    u.x = bf16bits(val.x); u.y = bf16bits(val.y);
    u.z = bf16bits(val.z); u.w = bf16bits(val.w);
    *(ushort4*)(dstS + (size_t)(by + r) * NN + bx + c4) = u;
  }
  __syncthreads();
  for (int it = 0; it < 4; ++it) {
    int c = (t >> 4) + it * 16;
    int r0 = (t & 15) * 4;
    ushort4 u;
    u.x = bf16bits(tile[r0][c]);
    u.y = bf16bits(tile[r0 + 1][c]);
    u.z = bf16bits(tile[r0 + 2][c]);
    u.w = bf16bits(tile[r0 + 3][c]);
    *(ushort4*)(dstT + (size_t)(bx + c) * NN + by + r0) = u;
  }
}

// ---------------------------------------------------------------------------
// C(128x128 fp32 tile) = A(row-major bf16) * Bt(row-major bf16 = B^T), BK=64.
// Split-K over blockIdx.z: each part writes its own partial buffer.
// LDS: 16 chunks/operand; chunk c = mt*2+h holds rows [mt*16,mt*16+16) x
// k-local [h*32, h*32+32): lane L wrote row mt*16+(L&15), k h*32+(L>>4)*8.
__global__ __launch_bounds__(256) void gemm_bt(
    const __hip_bfloat16* __restrict__ Ag,
    const __hip_bfloat16* __restrict__ Btg,
    float* __restrict__ Cg, int kLen) {
  __shared__ __align__(16) short As[8192];  // 16 KB
  __shared__ __align__(16) short Bs[8192];  // 16 KB

  const int tid = threadIdx.x;
  const int wave = tid >> 6;
  const int lane = tid & 63;
  const int rowBase = blockIdx.y * 128;
  const int colBase = blockIdx.x * 128;
  const int wr = wave >> 1, wc = wave & 1;
  const int lrow = lane & 15, lq = lane >> 4;
  const int kStart = blockIdx.z * kLen;
  float* Cout = Cg + (size_t)blockIdx.z * NN * NN;

  f32x4 acc[4][4];
  for (int i = 0; i < 4; ++i)
    for (int j = 0; j < 4; ++j) acc[i][j] = (f32x4){0.f, 0.f, 0.f, 0.f};

  // staging: wave handles chunks wave*4 .. wave*4+3 for both A and B
  const __hip_bfloat16* aS[4];
  const __hip_bfloat16* bS[4];
  short* aD[4];
  short* bD[4];
  for (int u = 0; u < 4; ++u) {
    int c = wave * 4 + u, mt = c >> 1, h = c & 1;
    aS[u] = Ag + (size_t)(rowBase + mt * 16 + lrow) * NN + h * 32 + lq * 8;
    bS[u] = Btg + (size_t)(colBase + mt * 16 + lrow) * NN + h * 32 + lq * 8;
    aD[u] = &As[c * 512];
    bD[u] = &Bs[c * 512];
  }

  for (int kt = kStart; kt < kStart + kLen; kt += 64) {
    for (int u = 0; u < 4; ++u) GLDS16(aS[u] + kt, aD[u]);
    for (int u = 0; u < 4; ++u) GLDS16(bS[u] + kt, bD[u]);
    __syncthreads();
    for (int h = 0; h < 2; ++h) {
      short8 af[4], bf[4];
      for (int i = 0; i < 4; ++i)
        af[i] = *(const short8*)&As[((wr * 4 + i) * 2 + h) * 512 + lane * 8];
      for (int j = 0; j < 4; ++j)
        bf[j] = *(const short8*)&Bs[((wc * 4 + j) * 2 + h) * 512 + lane * 8];
      for (int i = 0; i < 4; ++i)
        for (int j = 0; j < 4; ++j)
          acc[i][j] = __builtin_amdgcn_mfma_f32_16x16x32_bf16(
              af[i], bf[j], acc[i][j], 0, 0, 0);
    }
    __syncthreads();
  }
  // C/D layout: col = lane&15, row = (lane>>4)*4 + reg
  for (int i = 0; i < 4; ++i) {
    int r0 = rowBase + (wr * 4 + i) * 16 + lq * 4;
    for (int j = 0; j < 4; ++j) {
      int c0 = colBase + (wc * 4 + j) * 16 + lrow;
      for (int r = 0; r < 4; ++r)
        Cout[(size_t)(r0 + r) * NN + c0] = acc[i][j][r];
    }
  }
}

// ---------------------------------------------------------------------------
// Per-row top-64 via exact 31-bit radix select; one wave per row, float4
// loads, no LDS/barriers. M1 non-null => select over (M0+M1).
// outBf non-null => also write bf16(M0+M1) row (fused cast for next GEMM).
__global__ __launch_bounds__(256) void topk_rows(const float* __restrict__ M0,
                                                 const float* __restrict__ M1,
                                                 int* __restrict__ outCnt,
                                                 int* __restrict__ outIdx,
                                                 float* __restrict__ outVal,
                                                 __hip_bfloat16* __restrict__ outBf) {
  const int row = blockIdx.x * 4 + (threadIdx.x >> 6);
  const int lane = threadIdx.x & 63;
  const float4* r0 = (const float4*)(M0 + (size_t)row * NN);
  unsigned v[48];  // v[j*4+q] = col j*256 + lane*4 + q
  if (M1) {
    const float4* r1 = (const float4*)(M1 + (size_t)row * NN);
#pragma unroll
    for (int j = 0; j < 12; ++j) {
      float4 a = r0[lane + j * 64], b = r1[lane + j * 64];
      v[j * 4 + 0] = __float_as_uint(a.x + b.x);
      v[j * 4 + 1] = __float_as_uint(a.y + b.y);
      v[j * 4 + 2] = __float_as_uint(a.z + b.z);
      v[j * 4 + 3] = __float_as_uint(a.w + b.w);
    }
  } else {
#pragma unroll
    for (int j = 0; j < 12; ++j) {
      float4 a = r0[lane + j * 64];
      v[j * 4 + 0] = __float_as_uint(a.x);
      v[j * 4 + 1] = __float_as_uint(a.y);
      v[j * 4 + 2] = __float_as_uint(a.z);
      v[j * 4 + 3] = __float_as_uint(a.w);
    }
  }

  if (outBf) {
    __hip_bfloat16* ob = outBf + (size_t)row * NN;
#pragma unroll
    for (int j = 0; j < 12; ++j) {
      ushort4 u;
      u.x = bf16bits(__uint_as_float(v[j * 4 + 0]));
      u.y = bf16bits(__uint_as_float(v[j * 4 + 1]));
      u.z = bf16bits(__uint_as_float(v[j * 4 + 2]));
      u.w = bf16bits(__uint_as_float(v[j * 4 + 3]));
      *(ushort4*)(ob + j * 256 + lane * 4) = u;
    }
  }

  unsigned t = 0;
  for (int b = 30; b >= 0; --b) {
    unsigned cand = t | (1u << b);
    int c = 0;
#pragma unroll
    for (int r = 0; r < 48; ++r) c += (v[r] >= cand) ? 1 : 0;
    for (int off = 32; off; off >>= 1) c += __shfl_down(c, off, 64);
    c = __shfl(c, 0, 64);
    if (c >= 64) t = cand;
  }

  // ordered compaction via ballot
  int base = 0;
  int* oi = outIdx + (size_t)row * 128;
  float* ov = outVal + (size_t)row * 128;
#pragma unroll
  for (int r = 0; r < 48; ++r) {
    bool keep = v[r] >= t;
    unsigned long long m = __ballot(keep);
    if (keep) {
      int pos = base + __popcll(m & ((1ull << lane) - 1ull));
      if (pos < 128) {
        oi[pos] = (r >> 2) * 256 + lane * 4 + (r & 3);
        ov[pos] = __uint_as_float(v[r]);
      }
    }
    base += __popcll(m);
  }
  if (lane == 0) outCnt[row] = base < 128 ? base : 128;
}

// ---------------------------------------------------------------------------
__global__ __launch_bounds__(256) void matvec(const float* __restrict__ A,
                                              const float* __restrict__ x,
                                              const float* __restrict__ u,
                                              float* __restrict__ tout,
                                              float* __restrict__ wacc) {
  int row = blockIdx.x, tid = threadIdx.x;
  const float4* rp = (const float4*)(A + (size_t)row * NN);
  const float4* xp = (const float4*)x;
  float s = 0.f;
  for (int j = tid; j < NN / 4; j += 256) {
    float4 a = rp[j], b = xp[j];
    s += a.x * b.x + a.y * b.y + a.z * b.z + a.w * b.w;
  }
  for (int off = 32; off; off >>= 1) s += __shfl_down(s, off, 64);
  __shared__ float red[4];
  if ((tid & 63) == 0) red[tid >> 6] = s;
  __syncthreads();
  if (tid == 0) {
    float tot = red[0] + red[1] + red[2] + red[3];
    tout[row] = tot;
    atomicAdd(wacc, u[row] * tot);
  }
}

__global__ void dot_uv(const float* __restrict__ u, const float* __restrict__ v,
                       float* __restrict__ wacc0) {
  int tid = threadIdx.x;
  const float4* up = (const float4*)u;
  const float4* vp = (const float4*)v;
  float s = 0.f;
  for (int j = tid; j < NN / 4; j += 256) {
    float4 a = up[j], b = vp[j];
    s += a.x * b.x + a.y * b.y + a.z * b.z + a.w * b.w;
  }
  for (int off = 32; off; off >>= 1) s += __shfl_down(s, off, 64);
  __shared__ float red[4];
  if ((tid & 63) == 0) red[tid >> 6] = s;
  __syncthreads();
  if (tid == 0) wacc0[0] = red[0] + red[1] + red[2] + red[3];
}

__global__ void init_ws(float* wacc) {
  if (threadIdx.x < 4) wacc[threadIdx.x] = 0.f;
}

__global__ void attn_kernel(const float* __restrict__ wacc,
                            float* __restrict__ aw) {
  float w0 = wacc[0], w1 = wacc[1], w2 = wacc[2], w3 = wacc[3];
  float s = w0 + w1 + w2 + w3;
  w0 /= s; w1 /= s; w2 /= s; w3 /= s;
  float m = fmaxf(fmaxf(w0, w1), fmaxf(w2, w3));
  float e0 = expf(w0 - m), e1 = expf(w1 - m), e2 = expf(w2 - m),
        e3 = expf(w3 - m);
  float se = e0 + e1 + e2 + e3;
  aw[0] = e0 / se; aw[1] = e1 / se; aw[2] = e2 / se; aw[3] = e3 / se;
  aw[4] = GAMMA_F * (aw[1] + aw[2] + aw[3]);
}

// ---------------------------------------------------------------------------
static __device__ inline float ldE(const float* __restrict__ ue,
                                   const float* __restrict__ ie, int r, int d) {
  return r < NU ? ue[(size_t)r * DD + d] : ie[(size_t)(r - NU) * DD + d];
}

__global__ __launch_bounds__(128) void build_light(
    const float* __restrict__ uemb, const float* __restrict__ iemb,
    const float* __restrict__ uemb0, const float* __restrict__ iemb0,
    const float* __restrict__ aw, const int* __restrict__ cnts,
    const int* __restrict__ tIdx, const float* __restrict__ tVal,
    float* __restrict__ lightOut) {
  int row = blockIdx.x, d = threadIdx.x;
  float acc = aw[0] * ldE(uemb, iemb, row, d) +
              aw[4] * ldE(uemb0, iemb0, row, d);
  __shared__ int sIdx[128];
  __shared__ float sVal[128];
  for (int l = 0; l < 3; ++l) {
    int c = cnts[l * NN + row];
    const int* ip = tIdx + ((size_t)l * NN + row) * 128;
    const float* vp = tVal + ((size_t)l * NN + row) * 128;
    __syncthreads();
    if (d < c) { sIdx[d] = ip[d]; sVal[d] = vp[d]; }
    __syncthreads();
    float al = aw[l + 1];
    float la = 0.f;
    for (int k = 0; k < c; ++k) la += sVal[k] * ldE(uemb, iemb, sIdx[k], d);
    acc += al * la;
  }
  lightOut[(size_t)row * DD + d] = acc;
}

__global__ __launch_bounds__(64) void out_dot(const int* __restrict__ users,
                                              const int* __restrict__ items,
                                              const float* __restrict__ lightOut,
                                              float* __restrict__ out) {
  int b = blockIdx.x, lane = threadIdx.x;
  const float* up = lightOut + (size_t)users[b] * DD;
  const float* ip = lightOut + (size_t)(NU + items[b]) * DD;
  float s = up[lane] * ip[lane] + up[lane + 64] * ip[lane + 64];
  for (int off = 32; off; off >>= 1) s += __shfl_down(s, off, 64);
  if (lane == 0) out[b] = s;
}

// ---------------------------------------------------------------------------
extern "C" void kernel_launch(void* const* d_in, const int* in_sizes, int n_in,
                              void* d_out, int out_size, void* d_ws,
                              size_t ws_size, hipStream_t stream) {
  const int* users = (const int*)d_in[0];
  const int* items = (const int*)d_in[1];
  const float* A = (const float*)d_in[2];
  const float* uemb = (const float*)d_in[3];
  const float* iemb = (const float*)d_in[4];
  const float* uemb0 = (const float*)d_in[5];
  const float* iemb0 = (const float*)d_in[6];
  const float* vu = (const float*)d_in[7];
  const float* vv = (const float*)d_in[8];
  float* out = (float*)d_out;

  char* ws = (char*)d_ws;
  size_t off = 0;
  auto alloc = [&](size_t bytes) -> void* {
    void* p = ws + off;
    off += (bytes + 255) & ~(size_t)255;
    return p;
  };
  __hip_bfloat16* Abf = (__hip_bfloat16*)alloc((size_t)NN * NN * 2);
  __hip_bfloat16* Atb = (__hip_bfloat16*)alloc((size_t)NN * NN * 2);
  __hip_bfloat16* A2bf = (__hip_bfloat16*)alloc((size_t)NN * NN * 2);
  float* tvec = (float*)alloc((size_t)3 * NN * 4);
  float* wacc = (float*)alloc(256);
  float* aw = (float*)alloc(256);
  int* cnts = (int*)alloc((size_t)3 * NN * 4);
  int* tIdx = (int*)alloc((size_t)3 * NN * 128 * 4);
  float* tVal = (float*)alloc((size_t)3 * NN * 128 * 4);
  float* lightOut = (float*)alloc((size_t)NN * DD * 4);

  // split-K=2 if workspace holds two fp32 partial buffers, else 1
  const size_t cBytes = (size_t)NN * NN * 4;
  const bool split2 = (ws_size >= off + 2 * cBytes + 512);
  float* C0 = (float*)alloc(cBytes);
  float* C1 = split2 ? (float*)alloc(cBytes) : nullptr;
  const int kParts = split2 ? 2 : 1;
  const int kLen = NN / kParts;

  init_ws<<<1, 64, 0, stream>>>(wacc);

  // A -> bf16 straight (Abf) + transposed (Atb = A^T)
  conv_tr<<<dim3(48, 48), 256, 0, stream>>>(A, Abf, Atb);
  // A2 = A*A (fp32 partials); gemm_bt(A, Bt=A^T)
  gemm_bt<<<dim3(24, 24, kParts), 256, 0, stream>>>(Abf, Atb, C0, kLen);
  // top-64 of A (layer 0)
  topk_rows<<<NN / 4, 256, 0, stream>>>(A, nullptr, cnts, tIdx, tVal, nullptr);
  // top-64 of A2 (layer 1, fused partial sum) + fused bf16 cast of A2
  topk_rows<<<NN / 4, 256, 0, stream>>>(C0, C1, cnts + NN,
                                        tIdx + (size_t)NN * 128,
                                        tVal + (size_t)NN * 128, A2bf);
  // A3 = A2*A  (B^T = A^T already available!)
  gemm_bt<<<dim3(24, 24, kParts), 256, 0, stream>>>(A2bf, Atb, C0, kLen);
  topk_rows<<<NN / 4, 256, 0, stream>>>(C0, C1, cnts + 2 * NN,
                                        tIdx + (size_t)2 * NN * 128,
                                        tVal + (size_t)2 * NN * 128, nullptr);

  // attention weights: w = [u.v, u.Av, u.A2v, u.A3v]
  dot_uv<<<1, 256, 0, stream>>>(vu, vv, wacc);
  matvec<<<NN, 256, 0, stream>>>(A, vv, vu, tvec, wacc + 1);
  matvec<<<NN, 256, 0, stream>>>(A, tvec, vu, tvec + NN, wacc + 2);
  matvec<<<NN, 256, 0, stream>>>(A, tvec + NN, vu, tvec + 2 * NN, wacc + 3);
  attn_kernel<<<1, 1, 0, stream>>>(wacc, aw);

  build_light<<<NN, 128, 0, stream>>>(uemb, iemb, uemb0, iemb0, aw, cnts,
                                      tIdx, tVal, lightOut);
  out_dot<<<BB, 64, 0, stream>>>(users, items, lightOut, out);
}

// Round 4
// 545.717 us; speedup vs baseline: 1.3951x; 1.2440x over previous
//
#include <hip/hip_runtime.h>
#include <hip/hip_bf16.h>
#include <math.h>

#define NN 3072
#define NU 1024
#define NI 2048
#define DD 128
#define BB 8192
#define GAMMA_F 0.2f

typedef __attribute__((ext_vector_type(8))) short short8;
typedef __attribute__((ext_vector_type(4))) float f32x4;

// async global->LDS, 16B per lane; LDS dst = wave-uniform base + lane*16
#define GLDS16(g, l)                                                          \
  __builtin_amdgcn_global_load_lds(                                           \
      (__attribute__((address_space(1))) void*)(g),                           \
      (__attribute__((address_space(3))) void*)(l), 16, 0, 0)

static __device__ inline unsigned short bf16bits(float x) {
  union { __hip_bfloat16 h; unsigned short u; } cv;
  cv.h = __float2bfloat16(x);
  return cv.u;
}

// block-level sum of per-thread partial (256 threads), result on tid 0
static __device__ inline float block_sum(float s, float* red4) {
  int tid = threadIdx.x;
  for (int off = 32; off; off >>= 1) s += __shfl_down(s, off, 64);
  if ((tid & 63) == 0) red4[tid >> 6] = s;
  __syncthreads();
  return red4[0] + red4[1] + red4[2] + red4[3];
}

// ---------------------------------------------------------------------------
// Per-row top-64 of sum of `parts` fp32 partial matrices via exact 31-bit
// radix select; one wave per row, no LDS/barriers. outBf: fused bf16 cast.
static __device__ void topk_row_dev(const float* __restrict__ base, int parts,
                                    int row, int lane, int* __restrict__ outCnt,
                                    int* __restrict__ outIdx,
                                    float* __restrict__ outVal,
                                    __hip_bfloat16* __restrict__ outBf) {
  float f[48];
  const float4* r0 = (const float4*)(base + (size_t)row * NN);
#pragma unroll
  for (int j = 0; j < 12; ++j) {
    float4 a = r0[lane + j * 64];
    f[j * 4 + 0] = a.x; f[j * 4 + 1] = a.y;
    f[j * 4 + 2] = a.z; f[j * 4 + 3] = a.w;
  }
  for (int p = 1; p < parts; ++p) {
    const float4* rp =
        (const float4*)(base + (size_t)p * NN * NN + (size_t)row * NN);
#pragma unroll
    for (int j = 0; j < 12; ++j) {
      float4 a = rp[lane + j * 64];
      f[j * 4 + 0] += a.x; f[j * 4 + 1] += a.y;
      f[j * 4 + 2] += a.z; f[j * 4 + 3] += a.w;
    }
  }
  if (outBf) {
    __hip_bfloat16* ob = outBf + (size_t)row * NN;
#pragma unroll
    for (int j = 0; j < 12; ++j) {
      ushort4 u;
      u.x = bf16bits(f[j * 4 + 0]); u.y = bf16bits(f[j * 4 + 1]);
      u.z = bf16bits(f[j * 4 + 2]); u.w = bf16bits(f[j * 4 + 3]);
      *(ushort4*)(ob + j * 256 + lane * 4) = u;
    }
  }
  unsigned v[48];
#pragma unroll
  for (int r = 0; r < 48; ++r) v[r] = __float_as_uint(f[r]);

  unsigned t = 0;
  for (int b = 30; b >= 0; --b) {
    unsigned cand = t | (1u << b);
    int c = 0;
#pragma unroll
    for (int r = 0; r < 48; ++r) c += (v[r] >= cand) ? 1 : 0;
    for (int off = 32; off; off >>= 1) c += __shfl_down(c, off, 64);
    c = __shfl(c, 0, 64);
    if (c >= 64) t = cand;
  }
  int basec = 0;
  int* oi = outIdx + (size_t)row * 128;
  float* ov = outVal + (size_t)row * 128;
#pragma unroll
  for (int r = 0; r < 48; ++r) {
    bool keep = v[r] >= t;
    unsigned long long m = __ballot(keep);
    if (keep) {
      int pos = basec + __popcll(m & ((1ull << lane) - 1ull));
      if (pos < 128) {
        oi[pos] = (r >> 2) * 256 + lane * 4 + (r & 3);
        ov[pos] = __uint_as_float(v[r]);
      }
    }
    basec += __popcll(m);
  }
  if (lane == 0) outCnt[row] = basec < 128 ? basec : 128;
}

// fp32 row-dot: out = A[row,:] . x
static __device__ inline float row_dot_f32(const float* __restrict__ rowp,
                                           const float* __restrict__ x,
                                           float* red4) {
  const float4* rp = (const float4*)rowp;
  const float4* xp = (const float4*)x;
  float s = 0.f;
  for (int j = threadIdx.x; j < NN / 4; j += 256) {
    float4 a = rp[j], b = xp[j];
    s += a.x * b.x + a.y * b.y + a.z * b.z + a.w * b.w;
  }
  return block_sum(s, red4);
}

// ---------------------------------------------------------------------------
// prep: conv_tr (2304) | topk(A) (768) | y1 = A.v (3072) | w0 = u.v (1)
__global__ __launch_bounds__(256) void prep(
    const float* __restrict__ A, const float* __restrict__ vu,
    const float* __restrict__ vv, __hip_bfloat16* __restrict__ Abf,
    __hip_bfloat16* __restrict__ Atb, int* __restrict__ cnts,
    int* __restrict__ tIdx, float* __restrict__ tVal,
    float* __restrict__ y1, float* __restrict__ wacc) {
  __shared__ float sh[64 * 65];
  const int bid = blockIdx.x;
  const int t = threadIdx.x;
  if (bid < 2304) {
    // ---- convert + transpose 64x64 tile
    const int bx = (bid % 48) * 64, by = (bid / 48) * 64;
    const int rr = t >> 4;
    const int c4 = (t & 15) * 4;
    for (int it = 0; it < 4; ++it) {
      int r = rr + it * 16;
      float4 val = *(const float4*)(A + (size_t)(by + r) * NN + bx + c4);
      sh[r * 65 + c4] = val.x; sh[r * 65 + c4 + 1] = val.y;
      sh[r * 65 + c4 + 2] = val.z; sh[r * 65 + c4 + 3] = val.w;
      ushort4 u;
      u.x = bf16bits(val.x); u.y = bf16bits(val.y);
      u.z = bf16bits(val.z); u.w = bf16bits(val.w);
      *(ushort4*)(Abf + (size_t)(by + r) * NN + bx + c4) = u;
    }
    __syncthreads();
    for (int it = 0; it < 4; ++it) {
      int c = (t >> 4) + it * 16;
      int r0 = (t & 15) * 4;
      ushort4 u;
      u.x = bf16bits(sh[r0 * 65 + c]);
      u.y = bf16bits(sh[(r0 + 1) * 65 + c]);
      u.z = bf16bits(sh[(r0 + 2) * 65 + c]);
      u.w = bf16bits(sh[(r0 + 3) * 65 + c]);
      *(ushort4*)(Atb + (size_t)(bx + c) * NN + by + r0) = u;
    }
  } else if (bid < 3072) {
    int row = (bid - 2304) * 4 + (t >> 6);
    topk_row_dev(A, 1, row, t & 63, cnts, tIdx, tVal, nullptr);
  } else if (bid < 6144) {
    int row = bid - 3072;
    float s = row_dot_f32(A + (size_t)row * NN, vv, sh);
    if (t == 0) y1[row] = s;
  } else {
    float s = row_dot_f32(vu, vv, sh);  // u.v (both 3072 vecs)
    if (t == 0) wacc[0] = s;
  }
}

// ---------------------------------------------------------------------------
// gemm: C(128x128 tile) = A(row-major bf16) * Bt(row-major bf16 = B^T), BK=32.
// Split-K over blockIdx.z -> partial buffer z.
__global__ __launch_bounds__(256) void gemm_bt(
    const __hip_bfloat16* __restrict__ Ag,
    const __hip_bfloat16* __restrict__ Btg,
    float* __restrict__ Cg, int kLen) {
  __shared__ __align__(16) short As[4096];
  __shared__ __align__(16) short Bs[4096];

  const int tid = threadIdx.x;
  const int wave = tid >> 6;
  const int lane = tid & 63;
  const int rowBase = blockIdx.y * 128;
  const int colBase = blockIdx.x * 128;
  const int wr = wave >> 1, wc = wave & 1;
  const int lrow = lane & 15, lq = lane >> 4;
  const int kStart = blockIdx.z * kLen;
  float* Cout = Cg + (size_t)blockIdx.z * NN * NN;

  f32x4 acc[4][4];
  for (int i = 0; i < 4; ++i)
    for (int j = 0; j < 4; ++j) acc[i][j] = (f32x4){0.f, 0.f, 0.f, 0.f};

  const __hip_bfloat16* aSrc =
      Ag + (size_t)(rowBase + wave * 16 + lrow) * NN + lq * 8;
  const __hip_bfloat16* bSrc =
      Btg + (size_t)(colBase + wave * 16 + lrow) * NN + lq * 8;
  short* aD0 = &As[wave * 512];
  short* aD1 = &As[(4 + wave) * 512];
  short* bD0 = &Bs[wave * 512];
  short* bD1 = &Bs[(4 + wave) * 512];

  for (int kt = kStart; kt < kStart + kLen; kt += 32) {
    GLDS16(aSrc + kt, aD0);
    GLDS16(aSrc + (size_t)64 * NN + kt, aD1);
    GLDS16(bSrc + kt, bD0);
    GLDS16(bSrc + (size_t)64 * NN + kt, bD1);
    __syncthreads();
    short8 af[4], bf[4];
    for (int i = 0; i < 4; ++i)
      af[i] = *(const short8*)&As[(wr * 4 + i) * 512 + lane * 8];
    for (int j = 0; j < 4; ++j)
      bf[j] = *(const short8*)&Bs[(wc * 4 + j) * 512 + lane * 8];
    for (int i = 0; i < 4; ++i)
      for (int j = 0; j < 4; ++j)
        acc[i][j] = __builtin_amdgcn_mfma_f32_16x16x32_bf16(af[i], bf[j],
                                                            acc[i][j], 0, 0, 0);
    __syncthreads();
  }
  for (int i = 0; i < 4; ++i) {
    int r0 = rowBase + (wr * 4 + i) * 16 + lq * 4;
    for (int j = 0; j < 4; ++j) {
      int c0 = colBase + (wc * 4 + j) * 16 + lrow;
      for (int r = 0; r < 4; ++r)
        Cout[(size_t)(r0 + r) * NN + c0] = acc[i][j][r];
    }
  }
}

// ---------------------------------------------------------------------------
// post1: topk(A2)+cast (768) | y2 = A.y1 (3072) | s1 = At.u bf16 (3072) |
//        w1 = u.y1 (1)
__global__ __launch_bounds__(256) void post1(
    const float* __restrict__ C, int parts, const float* __restrict__ A,
    const __hip_bfloat16* __restrict__ Atb, const float* __restrict__ vu,
    const float* __restrict__ y1, __hip_bfloat16* __restrict__ A2bf,
    int* __restrict__ cnts, int* __restrict__ tIdx, float* __restrict__ tVal,
    float* __restrict__ y2, float* __restrict__ s1,
    float* __restrict__ wacc) {
  __shared__ float red4[4];
  const int bid = blockIdx.x;
  const int t = threadIdx.x;
  if (bid < 768) {
    int row = bid * 4 + (t >> 6);
    topk_row_dev(C, parts, row, t & 63, cnts, tIdx, tVal, A2bf);
  } else if (bid < 3840) {
    int row = bid - 768;
    float s = row_dot_f32(A + (size_t)row * NN, y1, red4);
    if (t == 0) y2[row] = s;
  } else if (bid < 6912) {
    int row = bid - 3840;  // s1[row] = Atb[row,:] . u   (= (A^T u)[row])
    const __hip_bfloat162* rp =
        (const __hip_bfloat162*)(Atb + (size_t)row * NN);
    const float2* up = (const float2*)vu;
    float s = 0.f;
    for (int j = t; j < NN / 2; j += 256) {
      float2 a = __bfloat1622float2(rp[j]);
      float2 b = up[j];
      s += a.x * b.x + a.y * b.y;
    }
    s = block_sum(s, red4);
    if (t == 0) s1[row] = s;
  } else {
    float s = row_dot_f32(vu, y1, red4);
    if (t == 0) wacc[1] = s;
  }
}

// ---------------------------------------------------------------------------
// post2: topk(A3) (768) | {w2 = u.y2, w3 = s1.y2} (1)
__global__ __launch_bounds__(256) void post2(
    const float* __restrict__ C, int parts, const float* __restrict__ vu,
    const float* __restrict__ y2, const float* __restrict__ s1,
    int* __restrict__ cnts, int* __restrict__ tIdx, float* __restrict__ tVal,
    float* __restrict__ wacc) {
  __shared__ float red4[4];
  const int bid = blockIdx.x;
  const int t = threadIdx.x;
  if (bid < 768) {
    int row = bid * 4 + (t >> 6);
    topk_row_dev(C, parts, row, t & 63, cnts, tIdx, tVal, nullptr);
  } else {
    float s2 = row_dot_f32(vu, y2, red4);
    if (t == 0) wacc[2] = s2;
    __syncthreads();
    float s3 = row_dot_f32(s1, y2, red4);
    if (t == 0) wacc[3] = s3;
  }
}

// ---------------------------------------------------------------------------
static __device__ inline float ldE(const float* __restrict__ ue,
                                   const float* __restrict__ ie, int r, int d) {
  return r < NU ? ue[(size_t)r * DD + d] : ie[(size_t)(r - NU) * DD + d];
}

__global__ __launch_bounds__(128) void build_light(
    const float* __restrict__ uemb, const float* __restrict__ iemb,
    const float* __restrict__ uemb0, const float* __restrict__ iemb0,
    const float* __restrict__ wacc, const int* __restrict__ cnts,
    const int* __restrict__ tIdx, const float* __restrict__ tVal,
    float* __restrict__ lightOut) {
  // attention weights (uniform tiny compute per block)
  float w0 = wacc[0], w1 = wacc[1], w2 = wacc[2], w3 = wacc[3];
  float ss = w0 + w1 + w2 + w3;
  w0 /= ss; w1 /= ss; w2 /= ss; w3 /= ss;
  float m = fmaxf(fmaxf(w0, w1), fmaxf(w2, w3));
  float e0 = expf(w0 - m), e1 = expf(w1 - m), e2 = expf(w2 - m),
        e3 = expf(w3 - m);
  float se = e0 + e1 + e2 + e3;
  float aw[4] = {e0 / se, e1 / se, e2 / se, e3 / se};
  float aw4 = GAMMA_F * (aw[1] + aw[2] + aw[3]);

  int row = blockIdx.x, d = threadIdx.x;
  float acc = aw[0] * ldE(uemb, iemb, row, d) +
              aw4 * ldE(uemb0, iemb0, row, d);
  __shared__ int sIdx[128];
  __shared__ float sVal[128];
  for (int l = 0; l < 3; ++l) {
    int c = cnts[l * NN + row];
    const int* ip = tIdx + ((size_t)l * NN + row) * 128;
    const float* vp = tVal + ((size_t)l * NN + row) * 128;
    __syncthreads();
    if (d < c) { sIdx[d] = ip[d]; sVal[d] = vp[d]; }
    __syncthreads();
    float al = aw[l + 1];
    float la = 0.f;
    for (int k = 0; k < c; ++k) la += sVal[k] * ldE(uemb, iemb, sIdx[k], d);
    acc += al * la;
  }
  lightOut[(size_t)row * DD + d] = acc;
}

__global__ __launch_bounds__(64) void out_dot(const int* __restrict__ users,
                                              const int* __restrict__ items,
                                              const float* __restrict__ lightOut,
                                              float* __restrict__ out) {
  int b = blockIdx.x, lane = threadIdx.x;
  const float* up = lightOut + (size_t)users[b] * DD;
  const float* ip = lightOut + (size_t)(NU + items[b]) * DD;
  float s = up[lane] * ip[lane] + up[lane + 64] * ip[lane + 64];
  for (int off = 32; off; off >>= 1) s += __shfl_down(s, off, 64);
  if (lane == 0) out[b] = s;
}

// ---------------------------------------------------------------------------
extern "C" void kernel_launch(void* const* d_in, const int* in_sizes, int n_in,
                              void* d_out, int out_size, void* d_ws,
                              size_t ws_size, hipStream_t stream) {
  const int* users = (const int*)d_in[0];
  const int* items = (const int*)d_in[1];
  const float* A = (const float*)d_in[2];
  const float* uemb = (const float*)d_in[3];
  const float* iemb = (const float*)d_in[4];
  const float* uemb0 = (const float*)d_in[5];
  const float* iemb0 = (const float*)d_in[6];
  const float* vu = (const float*)d_in[7];
  const float* vv = (const float*)d_in[8];
  float* out = (float*)d_out;

  char* ws = (char*)d_ws;
  size_t off = 0;
  auto alloc = [&](size_t bytes) -> void* {
    void* p = ws + off;
    off += (bytes + 255) & ~(size_t)255;
    return p;
  };
  __hip_bfloat16* Abf = (__hip_bfloat16*)alloc((size_t)NN * NN * 2);
  __hip_bfloat16* Atb = (__hip_bfloat16*)alloc((size_t)NN * NN * 2);
  // A2bf aliases Abf: Abf is dead after gemm1, A2bf written by post1.
  __hip_bfloat16* A2bf = Abf;
  float* y1 = (float*)alloc((size_t)NN * 4);
  float* y2 = (float*)alloc((size_t)NN * 4);
  float* s1 = (float*)alloc((size_t)NN * 4);
  float* wacc = (float*)alloc(256);
  int* cnts = (int*)alloc((size_t)3 * NN * 4);
  int* tIdx = (int*)alloc((size_t)3 * NN * 128 * 4);
  float* tVal = (float*)alloc((size_t)3 * NN * 128 * 4);
  float* lightOut = (float*)alloc((size_t)NN * DD * 4);

  const size_t cBytes = (size_t)NN * NN * 4;
  int kParts = 1;
  if (ws_size >= off + 4 * cBytes + 512) kParts = 4;
  else if (ws_size >= off + 2 * cBytes + 512) kParts = 2;
  float* C = (float*)alloc((size_t)kParts * cBytes);
  const int kLen = NN / kParts;

  // 1) prep: conv/transpose | topk(A) | y1=A.v | w0=u.v
  prep<<<2304 + 768 + 3072 + 1, 256, 0, stream>>>(A, vu, vv, Abf, Atb, cnts,
                                                  tIdx, tVal, y1, wacc);
  // 2) A2 = A*A
  gemm_bt<<<dim3(24, 24, kParts), 256, 0, stream>>>(Abf, Atb, C, kLen);
  // 3) post1: topk(A2)+cast | y2=A.y1 | s1=A^T u | w1=u.y1
  post1<<<768 + 3072 + 3072 + 1, 256, 0, stream>>>(
      C, kParts, A, Atb, vu, y1, A2bf, cnts + NN, tIdx + (size_t)NN * 128,
      tVal + (size_t)NN * 128, y2, s1, wacc);
  // 4) A3 = A2*A
  gemm_bt<<<dim3(24, 24, kParts), 256, 0, stream>>>(A2bf, Atb, C, kLen);
  // 5) post2: topk(A3) | w2,w3
  post2<<<768 + 1, 256, 0, stream>>>(C, kParts, vu, y2, s1, cnts + 2 * NN,
                                     tIdx + (size_t)2 * NN * 128,
                                     tVal + (size_t)2 * NN * 128, wacc);
  // 6) build light_out (attn inlined)
  build_light<<<NN, 128, 0, stream>>>(uemb, iemb, uemb0, iemb0, wacc, cnts,
                                      tIdx, tVal, lightOut);
  // 7) gather dots
  out_dot<<<BB, 64, 0, stream>>>(users, items, lightOut, out);
}